// Round 1
// baseline (5928.735 us; speedup 1.0000x reference)
//
#include <hip/hip_runtime.h>
#include <math.h>

// ---------------------------------------------------------------------------
// Graph wavelet network:
//   h = x @ W_in
//   per layer l: psi = sum_k w[l][k] * d_k,  d_0 = h, d_{k+1} = 0.5*(d_k + A D^-1 d_k)
//   y = LN(psi@W1+b1)*gamma+beta; y = gelu(y); h = y@W2+b2; out[:,l,:] = h
// C = 64 channels == one wavefront lane per channel.
// ---------------------------------------------------------------------------

#define CC 64

// ---- degree count over col (targets) ----
__global__ void count_deg(const int* __restrict__ col, float* __restrict__ deg, int E) {
    int e = blockIdx.x * blockDim.x + threadIdx.x;
    if (e < E) atomicAdd(&deg[col[e]], 1.0f);
}

__global__ void inv_deg(const float* __restrict__ deg, float* __restrict__ dinv, int N) {
    int i = blockIdx.x * blockDim.x + threadIdx.x;
    if (i < N) {
        float d = deg[i];
        dinv[i] = (d > 0.f) ? (1.0f / d) : 0.f;
    }
}

// ---- 3-kernel exclusive scan of deg -> ptr (N+1), cursor copy ----
__global__ void scan_blocks(const float* __restrict__ deg, int* __restrict__ ptr,
                            int* __restrict__ bsum, int N) {
    __shared__ int s[256];
    int t = threadIdx.x;
    int i = blockIdx.x * 256 + t;
    int v = (i < N) ? (int)deg[i] : 0;
    s[t] = v;
    __syncthreads();
    for (int off = 1; off < 256; off <<= 1) {
        int add = (t >= off) ? s[t - off] : 0;
        __syncthreads();
        s[t] += add;
        __syncthreads();
    }
    if (i < N) ptr[i] = s[t] - v;          // exclusive within block
    if (t == 255) bsum[blockIdx.x] = s[255];
}

__global__ void scan_top(int* __restrict__ bsum, int nb) {
    __shared__ int s[256];
    int t = threadIdx.x;
    int v = (t < nb) ? bsum[t] : 0;
    s[t] = v;
    __syncthreads();
    for (int off = 1; off < 256; off <<= 1) {
        int add = (t >= off) ? s[t - off] : 0;
        __syncthreads();
        s[t] += add;
        __syncthreads();
    }
    if (t < nb) bsum[t] = s[t] - v;        // exclusive block offsets
}

__global__ void scan_add(int* __restrict__ ptr, int* __restrict__ cursor,
                         const int* __restrict__ bsum, int N, int E) {
    int i = blockIdx.x * 256 + threadIdx.x;
    if (i < N) {
        int p = ptr[i] + bsum[blockIdx.x];
        ptr[i] = p;
        cursor[i] = p;
    }
    if (i == 0) ptr[N] = E;
}

// ---- bucket edges by destination (col); store src and weight deg_inv[src] ----
__global__ void build_csr(const int* __restrict__ row, const int* __restrict__ col,
                          const float* __restrict__ dinv, int* __restrict__ cursor,
                          int* __restrict__ src, float* __restrict__ wgt, int E) {
    int e = blockIdx.x * blockDim.x + threadIdx.x;
    if (e < E) {
        int c = col[e];
        int r = row[e];
        int pos = atomicAdd(&cursor[c], 1);
        src[pos] = r;
        wgt[pos] = dinv[r];
    }
}

// ---- h = x @ W_in (wave per row, W in LDS) ----
__global__ __launch_bounds__(256) void in_mm(const float* __restrict__ x,
                                             const float* __restrict__ Win,
                                             float* __restrict__ h, int N) {
    __shared__ float Ws[CC * CC];
    int t = threadIdx.x;
    for (int i = t; i < CC * CC; i += 256) Ws[i] = Win[i];
    __syncthreads();
    int lane = t & 63;
    int wave = (blockIdx.x * blockDim.x + t) >> 6;
    int nw = (gridDim.x * blockDim.x) >> 6;
    for (int n = wave; n < N; n += nw) {
        float xv = x[(size_t)n * CC + lane];
        float acc = 0.f;
#pragma unroll
        for (int d = 0; d < CC; ++d) {
            float xd = __shfl(xv, d, 64);
            acc += xd * Ws[d * CC + lane];
        }
        h[(size_t)n * CC + lane] = acc;
    }
}

// ---- psi = w_l[0] * h ----
__global__ void psi_init(const float* __restrict__ h, float* __restrict__ psi,
                         const float* __restrict__ wavelet, int l, int K1, int NC) {
    int i = blockIdx.x * blockDim.x + threadIdx.x;
    float w = wavelet[l * K1];
    if (l > 0) w -= wavelet[(l - 1) * K1];
    if (i < NC) psi[i] = w * h[i];
}

// ---- one diffusion step + fused wavelet accumulation ----
__global__ __launch_bounds__(256) void diffuse(const float* __restrict__ v,
                                               float* __restrict__ vn,
                                               float* __restrict__ psi,
                                               const int* __restrict__ ptr,
                                               const int* __restrict__ src,
                                               const float* __restrict__ wgt,
                                               const float* __restrict__ wavelet,
                                               int l, int k, int K1, int N) {
    int lane = threadIdx.x & 63;
    int wave = (blockIdx.x * blockDim.x + threadIdx.x) >> 6;
    int nw = (gridDim.x * blockDim.x) >> 6;
    float wk = wavelet[l * K1 + k];
    if (l > 0) wk -= wavelet[(l - 1) * K1 + k];
    for (int i = wave; i < N; i += nw) {
        int s0 = ptr[i], s1 = ptr[i + 1];
        float acc = 0.f;
        for (int j = s0; j < s1; ++j) {
            int s = src[j];
            float w = wgt[j];
            acc += w * v[(size_t)s * CC + lane];
        }
        float nx = 0.5f * (v[(size_t)i * CC + lane] + acc);
        vn[(size_t)i * CC + lane] = nx;
        psi[(size_t)i * CC + lane] += wk * nx;
    }
}

// ---- fused: y = LN(psi@W1+b1)*g+b; y = gelu(y); h = y@W2+b2; write h and out ----
__global__ __launch_bounds__(256) void mlp_fused(const float* __restrict__ psi,
                                                 float* __restrict__ hout,
                                                 float* __restrict__ out,
                                                 const float* __restrict__ W1,
                                                 const float* __restrict__ b1,
                                                 const float* __restrict__ gamma,
                                                 const float* __restrict__ beta,
                                                 const float* __restrict__ W2,
                                                 const float* __restrict__ b2,
                                                 int l, int N, int L) {
    __shared__ float W1s[CC * CC];
    __shared__ float W2s[CC * CC];
    __shared__ float b1s[CC], b2s[CC], gs[CC], bs[CC];
    int t = threadIdx.x;
    const float* W1l = W1 + (size_t)l * CC * CC;
    const float* W2l = W2 + (size_t)l * CC * CC;
    for (int i = t; i < CC * CC; i += 256) {
        W1s[i] = W1l[i];
        W2s[i] = W2l[i];
    }
    if (t < CC) {
        b1s[t] = b1[l * CC + t];
        b2s[t] = b2[l * CC + t];
        gs[t] = gamma[l * CC + t];
        bs[t] = beta[l * CC + t];
    }
    __syncthreads();
    int lane = t & 63;
    int wave = (blockIdx.x * blockDim.x + t) >> 6;
    int nw = (gridDim.x * blockDim.x) >> 6;
    for (int n = wave; n < N; n += nw) {
        float xv = psi[(size_t)n * CC + lane];
        float y = b1s[lane];
#pragma unroll
        for (int d = 0; d < CC; ++d) {
            float xd = __shfl(xv, d, 64);
            y += xd * W1s[d * CC + lane];
        }
        // layernorm over the 64 lanes
        float s = y;
#pragma unroll
        for (int off = 32; off > 0; off >>= 1) s += __shfl_xor(s, off, 64);
        float mu = s * (1.0f / CC);
        float diff = y - mu;
        float vs = diff * diff;
#pragma unroll
        for (int off = 32; off > 0; off >>= 1) vs += __shfl_xor(vs, off, 64);
        float var = vs * (1.0f / CC);
        float yn = diff * rsqrtf(var + 1e-5f) * gs[lane] + bs[lane];
        // exact gelu
        float g = 0.5f * yn * (1.0f + erff(yn * 0.70710678118654752440f));
        float h2 = b2s[lane];
#pragma unroll
        for (int d = 0; d < CC; ++d) {
            float gd = __shfl(g, d, 64);
            h2 += gd * W2s[d * CC + lane];
        }
        hout[(size_t)n * CC + lane] = h2;
        out[(size_t)n * L * CC + (size_t)l * CC + lane] = h2;
    }
}

extern "C" void kernel_launch(void* const* d_in, const int* in_sizes, int n_in,
                              void* d_out, int out_size, void* d_ws, size_t ws_size,
                              hipStream_t stream) {
    const float* x = (const float*)d_in[0];
    const int* ei = (const int*)d_in[1];
    // d_in[2] = batch, d_in[3] = num_graphs: unused — batch is sorted with equal
    // counts, so to_dense_batch is an identity reshape: out[n, l*C + c] = h_l[n, c].
    const float* W_in = (const float*)d_in[4];
    const float* wavelet = (const float*)d_in[5];
    const float* W1 = (const float*)d_in[6];
    const float* b1 = (const float*)d_in[7];
    const float* gamma = (const float*)d_in[8];
    const float* beta = (const float*)d_in[9];
    const float* W2 = (const float*)d_in[10];
    const float* b2 = (const float*)d_in[11];
    float* out = (float*)d_out;

    const int C = CC;
    const int N = in_sizes[0] / C;
    const int E = in_sizes[1] / 2;
    const int L = in_sizes[6] / (C * C);
    const int K1 = in_sizes[5] / L;   // K+1 diffusion coefficients per layer

    // workspace layout (256B aligned slices)
    char* p = (char*)d_ws;
    auto alloc = [&](size_t bytes) -> void* {
        void* r = (void*)p;
        p += (bytes + 255) & ~(size_t)255;
        return r;
    };
    float* deg    = (float*)alloc((size_t)N * 4);
    float* dinv   = (float*)alloc((size_t)N * 4);
    int*   ptr    = (int*)alloc(((size_t)N + 1) * 4);
    int*   cursor = (int*)alloc((size_t)N * 4);
    int*   bsum   = (int*)alloc(1024);
    int*   src    = (int*)alloc((size_t)E * 4);
    float* wgt    = (float*)alloc((size_t)E * 4);
    float* bufA   = (float*)alloc((size_t)N * C * 4);
    float* bufB   = (float*)alloc((size_t)N * C * 4);
    float* psi    = (float*)alloc((size_t)N * C * 4);

    const int* row = ei;
    const int* col = ei + E;

    hipMemsetAsync(deg, 0, (size_t)N * 4, stream);
    count_deg<<<(E + 255) / 256, 256, 0, stream>>>(col, deg, E);
    inv_deg<<<(N + 255) / 256, 256, 0, stream>>>(deg, dinv, N);

    int nb = (N + 255) / 256;   // 196 for N=50000; scan_top handles nb <= 256
    scan_blocks<<<nb, 256, 0, stream>>>(deg, ptr, bsum, N);
    scan_top<<<1, 256, 0, stream>>>(bsum, nb);
    scan_add<<<nb, 256, 0, stream>>>(ptr, cursor, bsum, N, E);
    build_csr<<<(E + 255) / 256, 256, 0, stream>>>(row, col, dinv, cursor, src, wgt, E);

    int rowBlocks = (N + 3) / 4;   // 4 waves (rows) per 256-thread block
    in_mm<<<rowBlocks, 256, 0, stream>>>(x, W_in, bufA, N);

    for (int l = 0; l < L; ++l) {
        int NC = N * C;
        psi_init<<<(NC + 255) / 256, 256, 0, stream>>>(bufA, psi, wavelet, l, K1, NC);
        float* vc = bufA;
        float* vn = bufB;
        for (int k = 1; k < K1; ++k) {
            diffuse<<<rowBlocks, 256, 0, stream>>>(vc, vn, psi, ptr, src, wgt,
                                                   wavelet, l, k, K1, N);
            float* tmp = vc; vc = vn; vn = tmp;
        }
        // new h -> bufA (also the next layer's d_0); out written in same pass
        mlp_fused<<<rowBlocks, 256, 0, stream>>>(psi, bufA, out, W1, b1, gamma, beta,
                                                 W2, b2, l, N, L);
    }
}